// Round 1
// baseline (1325.349 us; speedup 1.0000x reference)
//
#include <hip/hip_runtime.h>

// SpecAdaConv2d: out[b,co,h,w] = sum_{ci,kh,kw} (alpha[b,ci]*weight[co,ci,kh,kw]) * x[b,ci,h+kh-1,w+kw-1] + bias[co]
// Folded: conv(weight, alpha*x). fp32, VALU-bound (no fp32 MFMA on CDNA4).
//
// Block = one (b, 32x8 output tile); 256 threads, 1 pixel/thread, 64 co accs in VGPRs.
// Weights read with wave-uniform indices -> scalar loads (s_load), FMA uses SGPR operand.

#define BB   8
#define CIN  64
#define COUT 64
#define HH   256
#define WW   256

#define TW 32
#define TH 8

__global__ __launch_bounds__(256, 4) void spec_ada_conv_kernel(
    const float* __restrict__ x,      // (B, CIN, H, W)
    const float* __restrict__ alpha,  // (B, CIN)
    const float* __restrict__ w,      // (COUT, CIN, 3, 3)
    const float* __restrict__ bias,   // (COUT)
    float* __restrict__ out)          // (B, COUT, H, W)
{
    __shared__ float sx[(TH + 2) * (TW + 2)];  // 10 x 34 = 340 floats

    const int tid = threadIdx.x;
    const int tx  = tid & (TW - 1);   // 0..31
    const int ty  = tid >> 5;         // 0..7
    const int gx0 = blockIdx.x * TW;
    const int gy0 = blockIdx.y * TH;
    const int b   = blockIdx.z;

    float acc[COUT];
#pragma unroll
    for (int co = 0; co < COUT; ++co) acc[co] = 0.0f;

    const float* xb = x + (size_t)b * CIN * HH * WW;

    for (int ci = 0; ci < CIN; ++ci) {
        const float a = alpha[b * CIN + ci];   // wave-uniform -> scalar
        const float* xp = xb + ci * HH * WW;

        // Stage 10x34 halo tile, scaled by alpha. 340 elems / 256 threads.
#pragma unroll
        for (int k = 0; k < 2; ++k) {
            int i = tid + k * 256;
            if (i < (TH + 2) * (TW + 2)) {
                int r = i / (TW + 2);
                int c = i - r * (TW + 2);
                int gy = gy0 + r - 1;
                int gx = gx0 + c - 1;
                float v = 0.0f;
                if ((unsigned)gy < HH && (unsigned)gx < WW) v = xp[gy * WW + gx];
                sx[i] = v * a;
            }
        }
        __syncthreads();

        // 3x3 input patch into registers (2-way LDS bank aliasing only).
        float xv[9];
#pragma unroll
        for (int r = 0; r < 3; ++r)
#pragma unroll
            for (int c = 0; c < 3; ++c)
                xv[r * 3 + c] = sx[(ty + r) * (TW + 2) + (tx + c)];

        // 64 co x 9 FMAs; weight index is wave-uniform (loop constants) -> s_load.
#pragma unroll
        for (int co = 0; co < COUT; ++co) {
            const float* wp = w + ((size_t)(co * CIN + ci)) * 9;
            float s = acc[co];
            s = fmaf(wp[0], xv[0], s);
            s = fmaf(wp[1], xv[1], s);
            s = fmaf(wp[2], xv[2], s);
            s = fmaf(wp[3], xv[3], s);
            s = fmaf(wp[4], xv[4], s);
            s = fmaf(wp[5], xv[5], s);
            s = fmaf(wp[6], xv[6], s);
            s = fmaf(wp[7], xv[7], s);
            s = fmaf(wp[8], xv[8], s);
            acc[co] = s;
        }
        __syncthreads();  // protect sx before next ci overwrites it
    }

    // Epilogue: bias + store. Lanes 0..31 write 128B contiguous, lanes 32..63 next row.
    const int gy = gy0 + ty;
    const int gx = gx0 + tx;
    float* ob = out + (size_t)b * COUT * HH * WW + (size_t)gy * WW + gx;
#pragma unroll
    for (int co = 0; co < COUT; ++co) {
        ob[(size_t)co * HH * WW] = acc[co] + bias[co];
    }
}

extern "C" void kernel_launch(void* const* d_in, const int* in_sizes, int n_in,
                              void* d_out, int out_size, void* d_ws, size_t ws_size,
                              hipStream_t stream) {
    const float* x     = (const float*)d_in[0];
    const float* alpha = (const float*)d_in[1];
    const float* w     = (const float*)d_in[2];
    const float* bias  = (const float*)d_in[3];
    float* out = (float*)d_out;

    dim3 grid(WW / TW, HH / TH, BB);   // (8, 32, 8) = 2048 blocks
    dim3 block(256);
    spec_ada_conv_kernel<<<grid, block, 0, stream>>>(x, alpha, w, bias, out);
}

// Round 2
// 703.914 us; speedup vs baseline: 1.8828x; 1.8828x over previous
//
#include <hip/hip_runtime.h>

// SpecAdaConv2d: out[b,co,h,w] = conv2d(alpha[b,:]*x[b], weight) + bias
// fp32, no fp32 MFMA on CDNA4 -> VALU-bound, floor = 38.65 GFLOP / 157.3 TF = 246 us.
//
// R2 redesign after R1 post-mortem (VGPR_Count=44 -> acc[] was demoted to scratch,
// kernel was scratch-latency-bound at VALUBusy=22%):
//  - per-thread register tile 8co x 8px (64 accs) with small static unrolled loops
//  - weights staged per-ci into LDS as sw[k][co], read as float4 (ds_read_b128)
//  - x halo staged with row stride 36 (16B-aligned rows) -> b128/b64 reads
//  - no min-waves launch-bound cap; let allocator use ~100-130 VGPRs

#define BB   8
#define CIN  64
#define COUT 64
#define HH   256
#define WW   256

#define TW 32           // tile width (pixels)
#define TH 8            // tile height (pixels)
#define SS 36           // padded LDS row stride for x halo (mult of 4 -> 16B-aligned rows)

__global__ __launch_bounds__(256) void spec_ada_conv_kernel(
    const float* __restrict__ x,      // (B, CIN, H, W)
    const float* __restrict__ alpha,  // (B, CIN)
    const float* __restrict__ w,      // (COUT, CIN, 3, 3)
    const float* __restrict__ bias,   // (COUT)
    float* __restrict__ out)          // (B, COUT, H, W)
{
    __shared__ float sx[(TH + 2) * SS];   // 10 x 36 = 360 floats (halo tile, alpha-folded)
    __shared__ float sw[9 * COUT];        // [k][co] = 576 floats

    const int tid = threadIdx.x;
    const int pg  = tid & 3;              // pixel group -> px0 = pg*8
    const int py  = (tid >> 2) & 7;       // pixel row in tile
    const int cg  = tid >> 5;             // co group -> co0 = cg*8
    const int px0 = pg * 8;
    const int co0 = cg * 8;

    const int gx0 = blockIdx.x * TW;
    const int gy0 = blockIdx.y * TH;
    const int b   = blockIdx.z;

    float acc[8][8];
#pragma unroll
    for (int c = 0; c < 8; ++c)
#pragma unroll
        for (int p = 0; p < 8; ++p) acc[c][p] = 0.0f;

    const float* xb = x + (size_t)b * CIN * HH * WW;

    for (int ci = 0; ci < CIN; ++ci) {
        const float a = alpha[b * CIN + ci];
        const float* xp = xb + ci * HH * WW;

        // ---- stage x halo (10 x 34 used, stride 36), folded by alpha ----
#pragma unroll
        for (int k = 0; k < 2; ++k) {
            int i = tid + k * 256;
            if (i < (TH + 2) * (TW + 2)) {
                int r = i / (TW + 2);
                int c = i - r * (TW + 2);
                int gy = gy0 + r - 1;
                int gx = gx0 + c - 1;
                float v = 0.0f;
                if ((unsigned)gy < HH && (unsigned)gx < WW) v = xp[gy * WW + gx];
                sx[r * SS + c] = v * a;
            }
        }
        // ---- stage weights for this ci: sw[k*64 + co] ----
        {
            int i = tid;                      // 576 elems, 256 threads -> 2-3 each
#pragma unroll
            for (int k = 0; k < 3; ++k) {
                if (i < 9 * COUT) {
                    int co = i / 9;
                    int kk = i - co * 9;
                    sw[kk * COUT + co] = w[((size_t)co * CIN + ci) * 9 + kk];
                }
                i += 256;
            }
        }
        __syncthreads();

        // ---- compute: 3 kh x (row load + 3 kw x (w load + 64 FMA)) ----
#pragma unroll
        for (int kh = 0; kh < 3; ++kh) {
            // load 10-float row segment: sx[(py+kh)*SS + px0 .. px0+9]
            float xr[10];
            {
                const float4* p4 = (const float4*)&sx[(py + kh) * SS + px0];
                float4 v0 = p4[0];
                float4 v1 = p4[1];
                const float2* p2 = (const float2*)&sx[(py + kh) * SS + px0 + 8];
                float2 v2 = p2[0];
                xr[0] = v0.x; xr[1] = v0.y; xr[2] = v0.z; xr[3] = v0.w;
                xr[4] = v1.x; xr[5] = v1.y; xr[6] = v1.z; xr[7] = v1.w;
                xr[8] = v2.x; xr[9] = v2.y;
            }
#pragma unroll
            for (int kw = 0; kw < 3; ++kw) {
                const int k = kh * 3 + kw;
                float wv[8];
                {
                    const float4* q4 = (const float4*)&sw[k * COUT + co0];
                    float4 a0 = q4[0];
                    float4 a1 = q4[1];
                    wv[0] = a0.x; wv[1] = a0.y; wv[2] = a0.z; wv[3] = a0.w;
                    wv[4] = a1.x; wv[5] = a1.y; wv[6] = a1.z; wv[7] = a1.w;
                }
#pragma unroll
                for (int c = 0; c < 8; ++c)
#pragma unroll
                    for (int p = 0; p < 8; ++p)
                        acc[c][p] = fmaf(wv[c], xr[p + kw], acc[c][p]);
            }
        }
        __syncthreads();
    }

    // ---- epilogue: bias + coalesced float4 stores ----
    const int gy = gy0 + py;
    const int gx = gx0 + px0;
#pragma unroll
    for (int c = 0; c < 8; ++c) {
        const int co = co0 + c;
        const float bv = bias[co];
        float* ob = out + (((size_t)b * COUT + co) * HH + gy) * WW + gx;
        float4 s0 = make_float4(acc[c][0] + bv, acc[c][1] + bv, acc[c][2] + bv, acc[c][3] + bv);
        float4 s1 = make_float4(acc[c][4] + bv, acc[c][5] + bv, acc[c][6] + bv, acc[c][7] + bv);
        ((float4*)ob)[0] = s0;
        ((float4*)ob)[1] = s1;
    }
}

extern "C" void kernel_launch(void* const* d_in, const int* in_sizes, int n_in,
                              void* d_out, int out_size, void* d_ws, size_t ws_size,
                              hipStream_t stream) {
    const float* x     = (const float*)d_in[0];
    const float* alpha = (const float*)d_in[1];
    const float* w     = (const float*)d_in[2];
    const float* bias  = (const float*)d_in[3];
    float* out = (float*)d_out;

    dim3 grid(WW / TW, HH / TH, BB);   // (8, 32, 8) = 2048 blocks
    dim3 block(256);
    spec_ada_conv_kernel<<<grid, block, 0, stream>>>(x, alpha, w, bias, out);
}

// Round 3
// 587.535 us; speedup vs baseline: 2.2558x; 1.1981x over previous
//
#include <hip/hip_runtime.h>

// SpecAdaConv2d via split-bf16 MFMA implicit GEMM.
// out[b,co,p] = sum_{ci,k} (alpha[b,ci]*w[co,ci,k]) * x[b,ci,p+shift(k)] + bias[co]
// fp32 -> (hi,lo) bf16 split on both w and x; 3 products hi*hi + hi*lo_x + lo_w*hi
// (lo*lo dropped, ~2^-18 rel). 16x16x32 bf16 MFMA; matrix floor ~56 us.
//
// Kernel 1 (prepack_w): w -> fragment-ordered bf16 hi/lo planes in d_ws.
//   layout [chunk2][k9][plane2][mtile4][lane64][j8]; A-frag = 1 coalesced dwordx4.
// Kernel 2 (conv_mfma): per block: b, 32x8 px tile. 2 ci-chunks of 32:
//   stage halo 34x10 px * 32ci as bf16 hi/lo planes in LDS [px][ci] (stride 40),
//   then 9 k-shifts x 3 products of K=32 GEMM. Wave tile: 2 M-tiles x 8 N-tiles.

typedef __attribute__((ext_vector_type(8))) short short8;
typedef __attribute__((ext_vector_type(4))) float float4v;

#define BB 8
#define CI_N 64
#define CO_N 64
#define HH 256
#define WW 256
#define TW 32
#define TH 8
#define HALO_W 34
#define HALO_H 10
#define HALO_PX (HALO_W * HALO_H)   // 340
#define RS 40                        // LDS row stride, bf16 units (80 B, 16B-aligned)
#define PLANE (HALO_PX * RS)         // 13600 ushorts per plane

#define NFRAG (2 * 9 * 2 * 4 * 64 * 8)  // 73728 packed bf16 elems

__device__ __forceinline__ unsigned f2bf(float v) {
    unsigned u = __float_as_uint(v);
    return (u + 0x7FFFu + ((u >> 16) & 1u)) >> 16;   // RNE to bf16
}

__global__ void prepack_w(const float* __restrict__ w, ushort* __restrict__ wp) {
    int idx = blockIdx.x * 256 + threadIdx.x;
    if (idx >= NFRAG) return;
    int j     = idx & 7;
    int lane  = (idx >> 3) & 63;
    int mt    = (idx >> 9) & 3;
    int plane = (idx >> 11) & 1;
    int rest  = idx >> 12;            // chunk*9 + k, 0..17
    int k     = rest % 9;
    int chunk = rest / 9;
    int co = mt * 16 + (lane & 15);
    int ci = chunk * 32 + (lane >> 4) * 8 + j;
    float v = w[(co * CI_N + ci) * 9 + k];
    unsigned hi = f2bf(v);
    float fhi = __uint_as_float(hi << 16);
    unsigned lo = f2bf(v - fhi);
    wp[idx] = (ushort)(plane ? lo : hi);
}

__global__ __launch_bounds__(256) void conv_mfma(
    const float* __restrict__ x,      // (B, CIN, H, W)
    const float* __restrict__ alpha,  // (B, CIN)
    const ushort* __restrict__ wp,    // packed weights (d_ws)
    const float* __restrict__ bias,   // (COUT)
    float* __restrict__ out)          // (B, COUT, H, W)
{
    __shared__ __align__(16) ushort sx[2 * PLANE];  // hi plane, lo plane (54.4 KB)

    const int tid    = threadIdx.x;
    const int lane   = tid & 63;
    const int w_id   = tid >> 6;        // wave 0..3
    const int n_lane = lane & 15;
    const int q      = lane >> 4;
    const int b      = blockIdx.z;
    const int gx0    = blockIdx.x * TW;
    const int gy0    = blockIdx.y * TH;
    const int m_half = w_id & 1;        // owns M-tiles m_half*2 + {0,1}
    const int n_half = w_id >> 1;       // owns N-tiles n_half*8 + {0..7}

    // acc init = bias (C/D layout: col=lane&15 -> px, row=q*4+r -> co)
    float4v acc[2][8];
#pragma unroll
    for (int mt = 0; mt < 2; ++mt) {
        float4v bi;
#pragma unroll
        for (int r = 0; r < 4; ++r)
            bi[r] = bias[(m_half * 2 + mt) * 16 + q * 4 + r];
#pragma unroll
        for (int nt = 0; nt < 8; ++nt) acc[mt][nt] = bi;
    }

    const float* xb = x + (size_t)b * CI_N * HH * WW;
    // per-lane LDS base for B-frag reads (bf16 units): folds n_lane, q, n_half rows
    const int vbase = (n_half * 4 * HALO_W + n_lane) * RS + q * 8;

    for (int chunk = 0; chunk < 2; ++chunk) {
        if (chunk) __syncthreads();   // LDS reuse fence

        // ---- stage: wave w handles ci-pairs (w*4+p)*2 for p in 0..3 ----
#pragma unroll
        for (int p = 0; p < 4; ++p) {
            const int cl = (w_id * 4 + p) * 2;       // 0..30, even
            const int ci = chunk * 32 + cl;
            const float a0 = alpha[b * CI_N + ci];
            const float a1 = alpha[b * CI_N + ci + 1];
            const float* xp0 = xb + (size_t)ci * HH * WW;
            const float* xp1 = xp0 + HH * WW;
#pragma unroll
            for (int it = 0; it < 6; ++it) {
                int hp = it * 64 + lane;
                if (hp < HALO_PX) {
                    int hy = hp / HALO_W;
                    int hx = hp - hy * HALO_W;
                    int gy = gy0 - 1 + hy;
                    int gx = gx0 - 1 + hx;
                    bool ok = ((unsigned)gy < HH) & ((unsigned)gx < WW);
                    int gidx = gy * WW + gx;
                    float v0 = ok ? xp0[gidx] * a0 : 0.0f;
                    float v1 = ok ? xp1[gidx] * a1 : 0.0f;
                    unsigned h0 = f2bf(v0);
                    unsigned h1 = f2bf(v1);
                    float f0 = __uint_as_float(h0 << 16);
                    float f1 = __uint_as_float(h1 << 16);
                    unsigned l0 = f2bf(v0 - f0);
                    unsigned l1 = f2bf(v1 - f1);
                    *(unsigned*)&sx[hp * RS + cl]         = h0 | (h1 << 16);
                    *(unsigned*)&sx[PLANE + hp * RS + cl] = l0 | (l1 << 16);
                }
            }
        }
        __syncthreads();

        // ---- compute: 9 shifts x (hi*hi, lo_w*hi, hi*lo_x) over K=32 ci ----
#pragma unroll
        for (int k = 0; k < 9; ++k) {
            const int dy = k / 3 - 1;
            const int dx = k % 3 - 1;
            // A-frags: coalesced dwordx4 from packed layout (L2-resident)
            short8 a_hi[2], a_lo[2];
#pragma unroll
            for (int mt = 0; mt < 2; ++mt) {
                int fh = ((chunk * 9 + k) * 2 + 0) * 4 + (m_half * 2 + mt);
                int fl = ((chunk * 9 + k) * 2 + 1) * 4 + (m_half * 2 + mt);
                a_hi[mt] = *(const short8*)(wp + (size_t)(fh * 64 + lane) * 8);
                a_lo[mt] = *(const short8*)(wp + (size_t)(fl * 64 + lane) * 8);
            }
#pragma unroll
            for (int nt_i = 0; nt_i < 8; ++nt_i) {
                // halo px for this N-tile + shift; vbase carries n_half/n_lane/q
                const int off = ((nt_i >> 1) + 1 + dy) * HALO_W + 1 + (nt_i & 1) * 16 + dx;
                const ushort* bp = &sx[vbase + off * RS];
                short8 b_hi = *(const short8*)bp;
                short8 b_lo = *(const short8*)(bp + PLANE);
                acc[0][nt_i] = __builtin_amdgcn_mfma_f32_16x16x32_bf16(a_hi[0], b_hi, acc[0][nt_i], 0, 0, 0);
                acc[1][nt_i] = __builtin_amdgcn_mfma_f32_16x16x32_bf16(a_hi[1], b_hi, acc[1][nt_i], 0, 0, 0);
                acc[0][nt_i] = __builtin_amdgcn_mfma_f32_16x16x32_bf16(a_lo[0], b_hi, acc[0][nt_i], 0, 0, 0);
                acc[1][nt_i] = __builtin_amdgcn_mfma_f32_16x16x32_bf16(a_lo[1], b_hi, acc[1][nt_i], 0, 0, 0);
                acc[0][nt_i] = __builtin_amdgcn_mfma_f32_16x16x32_bf16(a_hi[0], b_lo, acc[0][nt_i], 0, 0, 0);
                acc[1][nt_i] = __builtin_amdgcn_mfma_f32_16x16x32_bf16(a_hi[1], b_lo, acc[1][nt_i], 0, 0, 0);
            }
        }
    }

    // ---- epilogue: store (64B-segment coalescing: 16 px x 4 co groups) ----
#pragma unroll
    for (int mt = 0; mt < 2; ++mt) {
        const int m0 = (m_half * 2 + mt) * 16;
#pragma unroll
        for (int nt_i = 0; nt_i < 8; ++nt_i) {
            const int nt = n_half * 8 + nt_i;
            const int gy = gy0 + (nt >> 1);
            const int gx = gx0 + (nt & 1) * 16 + n_lane;
#pragma unroll
            for (int r = 0; r < 4; ++r) {
                const int co = m0 + q * 4 + r;
                out[(((size_t)b * CO_N + co) * HH + gy) * WW + gx] = acc[mt][nt_i][r];
            }
        }
    }
}

extern "C" void kernel_launch(void* const* d_in, const int* in_sizes, int n_in,
                              void* d_out, int out_size, void* d_ws, size_t ws_size,
                              hipStream_t stream) {
    const float* x     = (const float*)d_in[0];
    const float* alpha = (const float*)d_in[1];
    const float* w     = (const float*)d_in[2];
    const float* bias  = (const float*)d_in[3];
    float* out  = (float*)d_out;
    ushort* wpk = (ushort*)d_ws;

    prepack_w<<<dim3((NFRAG + 255) / 256), dim3(256), 0, stream>>>(w, wpk);

    dim3 grid(WW / TW, HH / TH, BB);   // (8, 32, 8) = 2048 blocks
    conv_mfma<<<grid, dim3(256), 0, stream>>>(x, alpha, wpk, bias, out);
}